// Round 4
// baseline (231.461 us; speedup 1.0000x reference)
//
#include <hip/hip_runtime.h>

// SoftEmbeddedDecisionRules: balanced binary hierarchy over C=1024 classes.
// out[b,c] = prod over 10 levels of 2-way softmax prob of c's branch;
// 2-way softmax == sigmoid(diff of child means).
//
// R4 = R3 with the nontemporal-store type fixed (native ext_vector_type).
// ONE WAVE PER ROW, persistent grid-stride, zero LDS, zero barriers. Lane
// holds 4 quads (one per 256-class quarter) via 4 coalesced float4 loads
// (64 B MLP per lane). Levels 9,8 in registers; levels 7..2 via a 6-step
// __shfl_xor butterfly run on all 4 quarters at once; levels 1,0 from the
// 4 quarter sums, computed redundantly in every lane.

#define C 1024

typedef float f4 __attribute__((ext_vector_type(4)));

__device__ __forceinline__ float sigd(float d) {  // 1/(1+exp(d))
    return 1.0f / (1.0f + __expf(d));
}

__global__ __launch_bounds__(256) void hier_softmax_kernel(
    const float* __restrict__ in, float* __restrict__ out, int B) {
    const int lane = threadIdx.x & 63;
    const int waveId = (blockIdx.x * blockDim.x + threadIdx.x) >> 6;
    const int nWaves = (gridDim.x * blockDim.x) >> 6;

    for (int row = waveId; row < B; row += nWaves) {
        const f4* __restrict__ rowp = (const f4*)(in + (size_t)row * C);

        // 4 independent coalesced loads: quarter q, lane's quad = classes
        // [q*256 + lane*4, +4)
        f4 v[4];
#pragma unroll
        for (int q = 0; q < 4; ++q) v[q] = rowp[q * 64 + lane];

        float pA[4], pB[4], p8[4], S[4], common[4];
#pragma unroll
        for (int q = 0; q < 4; ++q) {
            pA[q] = sigd(v[q].y - v[q].x);            // level 9, left pair
            pB[q] = sigd(v[q].w - v[q].z);            // level 9, right pair
            const float s2a = v[q].x + v[q].y;
            const float s2b = v[q].z + v[q].w;
            p8[q] = sigd((s2b - s2a) * 0.5f);          // level 8 (quad node)
            S[q] = s2a + s2b;
            common[q] = 1.0f;
        }

        // levels 7..2: butterfly over the 64 quads of each quarter
        float inv = 0.25f;
#pragma unroll
        for (int m = 1; m <= 32; m <<= 1) {
#pragma unroll
            for (int q = 0; q < 4; ++q) {
                const float sib = __shfl_xor(S[q], m, 64);
                common[q] *= sigd((sib - S[q]) * inv);  // p(own branch)
                S[q] += sib;
            }
            inv *= 0.5f;
        }
        // S[q] = quarter sums, identical across lanes
        const float topL = sigd(((S[2] + S[3]) - (S[0] + S[1])) * (1.0f / 512.0f));
        const float pq01 = sigd((S[1] - S[0]) * (1.0f / 256.0f));
        const float pq23 = sigd((S[3] - S[2]) * (1.0f / 256.0f));
        const float lvl01[4] = {topL * pq01, topL * (1.0f - pq01),
                                (1.0f - topL) * pq23, (1.0f - topL) * (1.0f - pq23)};

        f4* __restrict__ orow = (f4*)(out + (size_t)row * C);
#pragma unroll
        for (int q = 0; q < 4; ++q) {
            const float cm = common[q] * lvl01[q];
            const float cl = cm * p8[q];
            const float cr = cm * (1.0f - p8[q]);
            f4 o;
            o.x = cl * pA[q];
            o.y = cl * (1.0f - pA[q]);
            o.z = cr * pB[q];
            o.w = cr * (1.0f - pB[q]);
            __builtin_nontemporal_store(o, orow + q * 64 + lane);
        }
    }
}

extern "C" void kernel_launch(void* const* d_in, const int* in_sizes, int n_in,
                              void* d_out, int out_size, void* d_ws, size_t ws_size,
                              hipStream_t stream) {
    const float* in = (const float*)d_in[0];
    float* out = (float*)d_out;
    const int B = in_sizes[0] / C;  // 32768
    hier_softmax_kernel<<<2048, 256, 0, stream>>>(in, out, B);
}